// Round 11
// baseline (244.607 us; speedup 1.0000x reference)
//
#include <hip/hip_runtime.h>

#define BATCH 8
#define NTOK 1032
#define NPAD 1152
#define MTOT (BATCH*NTOK)   // 8256
#define MPAD 8448           // 33 * 256

#define SCALE_Q 0.18033688011112042f   // 0.125 * log2(e)
#define C2      5.770780163555854f     // 4 * log2(e)

typedef __bf16 bf16x8 __attribute__((ext_vector_type(8)));
typedef float f32x4 __attribute__((ext_vector_type(4)));
typedef unsigned short us8 __attribute__((ext_vector_type(8)));
typedef unsigned short us4 __attribute__((ext_vector_type(4)));
typedef short s4 __attribute__((ext_vector_type(4)));

__device__ __forceinline__ unsigned short f2bf(float f){
  unsigned int u = __builtin_bit_cast(unsigned int, f);
  u += 0x7fffu + ((u >> 16) & 1u);          // RNE
  return (unsigned short)(u >> 16);
}
__device__ __forceinline__ float bf2f(unsigned short u){
  return __builtin_bit_cast(float, (unsigned int)u << 16);
}

#define MFMA16(a,b,c) __builtin_amdgcn_mfma_f32_16x16x32_bf16( \
    __builtin_bit_cast(bf16x8,(a)), __builtin_bit_cast(bf16x8,(b)), (c), 0, 0, 0)
#define MFMAH(a,b,c) __builtin_amdgcn_mfma_f32_16x16x16bf16_1k( \
    __builtin_bit_cast(s4,(a)), __builtin_bit_cast(s4,(b)), (c), 0, 0, 0)

__device__ __forceinline__ void gl_lds16(const unsigned short* g, unsigned short* l){
  __builtin_amdgcn_global_load_lds(
      (const __attribute__((address_space(1))) unsigned int*)g,
      (__attribute__((address_space(3))) unsigned int*)l, 16, 0, 0);
}

// ---------------- prep: fused fp32->bf16 conversions + pad zeroing ----------------
__global__ __launch_bounds__(256) void prep(
    const float* __restrict__ x, const float* __restrict__ qw, const float* __restrict__ pw,
    unsigned short* __restrict__ x_bf, unsigned short* __restrict__ qw_bf,
    unsigned short* __restrict__ pw_bf,
    unsigned short* __restrict__ qb, unsigned short* __restrict__ kb,
    unsigned short* __restrict__ ao)
{
  int i = blockIdx.x * 256 + threadIdx.x;
  const int n4x = MTOT * 1024 / 4;
  const int n4q = 3072 * 1024 / 4;
  const int n4p = 1024 * 1024 / 4;
  const int c1 = n4x, c2 = c1 + n4q, c3 = c2 + n4p;
  const int t1 = c3 + 128 * (NPAD - NTOK) * 64;
  const int t2 = t1 + (MPAD - MTOT) * 1024;
  const int t3 = t2 + (MPAD - MTOT) * 1024;

  if (i < c3){
    const float* src; unsigned short* dst; int j;
    if (i < c1){ src = x;  dst = x_bf;  j = i; }
    else if (i < c2){ src = qw; dst = qw_bf; j = i - c1; }
    else { src = pw; dst = pw_bf; j = i - c2; }
    float4 v = reinterpret_cast<const float4*>(src)[j];
    us4 o; o.x = f2bf(v.x); o.y = f2bf(v.y); o.z = f2bf(v.z); o.w = f2bf(v.w);
    reinterpret_cast<us4*>(dst)[j] = o;
  } else if (i < t1){
    int j = i - c3;
    int bh = j / ((NPAD - NTOK) * 64);
    int r  = (j / 64) % (NPAD - NTOK);
    int d  = j % 64;
    int idx = (bh * NPAD + NTOK + r) * 64 + d;
    qb[idx] = 0;
    kb[idx] = 0;
  } else if (i < t2){
    x_bf[(size_t)MTOT * 1024 + (i - t1)] = 0;
  } else if (i < t3){
    ao[(size_t)MTOT * 1024 + (i - t2)] = 0;
  }
}

// ---------------- QKV GEMM: 256x128 tile, 8 waves, counted-vmcnt 2-phase, swizzled LDS ----------------
__global__ __launch_bounds__(512,4) void qkv_gemm(
    const unsigned short* __restrict__ A,   // [MPAD][1024] bf16
    const unsigned short* __restrict__ Bw,  // [3072][1024] bf16
    const float* __restrict__ bias,         // [3072]
    unsigned short* __restrict__ qb,        // [128][NPAD][64]  (q pre-scaled by SCALE_Q)
    unsigned short* __restrict__ kb,        // [128][NPAD][64]
    unsigned short* __restrict__ vb)        // [128][NTOK][64]  (normal layout; transposed later)
{
  const int K = 1024;
  __shared__ __align__(16) unsigned short As[2][256*32];   // 16 KB per buf
  __shared__ __align__(16) unsigned short Bs[2][128*32];   // 8 KB per buf
  int tid = threadIdx.x;
  int id = blockIdx.x;
  int work = (id & 7) * 99 + (id >> 3);        // 792 = 8 * 99, bijective
  int m0 = (work / 24) * 256, n0 = (work % 24) * 128;
  int w = tid >> 6, lane = tid & 63, lr = lane & 15, lg = lane >> 4;
  int wr = w >> 1, wc = w & 1;                 // 4M x 2N waves; per-wave 64x64 out
  int srow = lane >> 2;
  int scol = ((lane & 3) ^ ((lane >> 3) & 3)) * 8;   // pre-swizzled source slot
  int sa = (lg ^ ((lr >> 1) & 3)) * 8;               // read-side involution
  f32x4 acc[4][4] = {};

  auto stage = [&](int buf, int k0){
    gl_lds16(&A [(size_t)(m0 + w*32      + srow) * K + k0 + scol], &As[buf][(w*2  )*512]);
    gl_lds16(&A [(size_t)(m0 + w*32 + 16 + srow) * K + k0 + scol], &As[buf][(w*2+1)*512]);
    gl_lds16(&Bw[(size_t)(n0 + w*16      + srow) * K + k0 + scol], &Bs[buf][ w      *512]);
  };

  stage(0, 0);   // prologue: tile 0 in flight (3 loads/wave)

  for (int kt = 0; kt < 32; kt++){
    int cur = kt & 1;
    if (kt < 31){
      stage(cur ^ 1, (kt + 1) * 32);
      asm volatile("s_waitcnt vmcnt(3)" ::: "memory");   // tile kt landed; kt+1 in flight
    } else {
      asm volatile("s_waitcnt vmcnt(0)" ::: "memory");
    }
    __builtin_amdgcn_sched_barrier(0);
    __builtin_amdgcn_s_barrier();                        // tile kt visible to all waves

    us8 a[4], b[4];
    #pragma unroll
    for (int mi = 0; mi < 4; mi++) a[mi] = *reinterpret_cast<const us8*>(&As[cur][(wr*64 + mi*16 + lr)*32 + sa]);
    #pragma unroll
    for (int ni = 0; ni < 4; ni++) b[ni] = *reinterpret_cast<const us8*>(&Bs[cur][(wc*64 + ni*16 + lr)*32 + sa]);
    #pragma unroll
    for (int mi = 0; mi < 4; mi++)
      #pragma unroll
      for (int ni = 0; ni < 4; ni++)
        acc[mi][ni] = MFMA16(a[mi], b[ni], acc[mi][ni]);
    __builtin_amdgcn_s_barrier();                        // reads of cur done; next iter overwrites
  }

  // epilogue: q/k into padded [bh][n][64]; v into normal [bh][n][64]
  #pragma unroll
  for (int mi = 0; mi < 4; mi++){
    #pragma unroll
    for (int ni = 0; ni < 4; ni++){
      #pragma unroll
      for (int reg = 0; reg < 4; reg++){
        int m = m0 + wr*64 + mi*16 + lg*4 + reg;
        if (m >= MTOT) continue;
        int n = n0 + wc*64 + ni*16 + lr;
        float val = acc[mi][ni][reg] + bias[n];
        int b_ = m / NTOK, nidx = m % NTOK;
        int t = n >> 10, h = (n >> 6) & 15, d = n & 63;
        int bh = h * BATCH + b_;
        if (t == 0){
          qb[(size_t)(bh * NPAD + nidx) * 64 + d] = f2bf(val * SCALE_Q);
        } else if (t == 1){
          kb[(size_t)(bh * NPAD + nidx) * 64 + d] = f2bf(val);
        } else {
          vb[(size_t)(bh * NTOK + nidx) * 64 + d] = f2bf(val);
        }
      }
    }
  }
}

// ---------------- V transpose: vb [bh][n][64] -> vt [bh][64][NPAD] ----------------
__global__ __launch_bounds__(256) void transpose_v(const unsigned short* __restrict__ vb,
                                                   unsigned short* __restrict__ vt){
  __shared__ unsigned short Ls[64][72];
  int blk = blockIdx.x;
  int bh = blk / 17, tl = blk % 17;
  int n0 = tl * 64;
  int t = threadIdx.x;

  #pragma unroll
  for (int p = 0; p < 2; p++){
    int idx = p * 256 + t;
    int r = idx >> 3, c = idx & 7;
    us8 v = {};
    if (n0 + r < NTOK)
      v = *reinterpret_cast<const us8*>(&vb[((size_t)bh * NTOK + n0 + r) * 64 + c * 8]);
    *reinterpret_cast<us8*>(&Ls[r][c * 8]) = v;
  }
  __syncthreads();

  int d = t & 63, ng = t >> 6;
  us8 o[2];
  #pragma unroll
  for (int hf = 0; hf < 2; hf++){
    #pragma unroll
    for (int j = 0; j < 8; j++) o[hf][j] = Ls[ng*16 + hf*8 + j][d];
    *reinterpret_cast<us8*>(&vt[((size_t)bh * 64 + d) * NPAD + n0 + ng*16 + hf*8]) = o[hf];
  }
}

// ---------------- flash attention v7: v6 with RWc overlaid on Vs[1] (LDS 48->40KB, 4 blocks/CU) ----------------
__global__ __launch_bounds__(256,4) void attn_kernel(
    const unsigned short* __restrict__ qb,
    const unsigned short* __restrict__ kb,
    const unsigned short* __restrict__ vt,
    const float* __restrict__ rph,   // [63][64]
    const float* __restrict__ rpw,   // [63][64]
    unsigned short* __restrict__ ao) // [MPAD][1024], rows b*NTOK+n
{
  __shared__ __align__(16) unsigned short Ks[2][64*64];   // 16 KB
  __shared__ __align__(16) unsigned short Vs[2][64*64];   // 16 KB
  __shared__ unsigned short RHt[32*128];                  // 8 KB, persistent
  // RWc is transient (consumed into rwreg before the K-loop): overlay on Vs[1],
  // which is first written by iter-0's stage — issued after the __syncthreads below.
  unsigned short* RWc = &Vs[1][0];                        // 8 KB scratch, no extra LDS

  int id = blockIdx.x;
  int work = (id & 7) * 144 + (id >> 3);
  int bh = work / 9;
  int qt = work % 9;
  int tid = threadIdx.x, w = tid >> 6, lane = tid & 63, lr = lane & 15, lg = lane >> 4;
  int h = bh >> 3, b_ = bh & 7;

  const unsigned short* qbase = qb + (size_t)bh * NPAD * 64;
  const unsigned short* kbase = kb + (size_t)bh * NPAD * 64;
  const unsigned short* vbase = vt + (size_t)bh * 64 * NPAD;

  // stage kt=0 into buf 0 only (Vs[1] still scratch)
  #pragma unroll
  for (int t = 0; t < 2; t++){
    int i = t*256 + tid;
    int row = i >> 3, cs = (i & 7) ^ (row & 7);
    gl_lds16(&kbase[(size_t)row*64 + cs*8],   &Ks[0][(t*256 + w*64)*8]);
    gl_lds16(&vbase[(size_t)row*NPAD + cs*8], &Vs[0][(t*256 + w*64)*8]);
  }

  us8 aq[2][2];
  #pragma unroll
  for (int qf = 0; qf < 2; qf++){
    int qrow = qt*128 + w*32 + qf*16 + lr;
    aq[qf][0] = *reinterpret_cast<const us8*>(&qbase[(size_t)qrow*64 + lg*8]);
    aq[qf][1] = *reinterpret_cast<const us8*>(&qbase[(size_t)qrow*64 + 32 + lg*8]);
  }

  float rwreg[2][2][4] = {};

  if (qt < 8){
    int qh = qt*4 + w;
    f32x4 accH[2][2] = {};
    #pragma unroll
    for (int ks = 0; ks < 2; ks++){
      #pragma unroll
      for (int nf2 = 0; nf2 < 2; nf2++){
        int t = nf2*16 + lr;
        const float* src = rph + (size_t)(qh - t + 31)*64 + ks*32 + lg*8;
        us8 ar;
        #pragma unroll
        for (int j = 0; j < 8; j++) ar[j] = f2bf(src[j]);
        #pragma unroll
        for (int qf = 0; qf < 2; qf++) accH[qf][nf2] = MFMA16(ar, aq[qf][ks], accH[qf][nf2]);
      }
    }
    #pragma unroll
    for (int qf = 0; qf < 2; qf++)
      #pragma unroll
      for (int nf2 = 0; nf2 < 2; nf2++)
        #pragma unroll
        for (int reg = 0; reg < 4; reg++){
          int t_out = nf2*16 + lg*4 + reg;
          RHt[t_out*128 + w*32 + qf*16 + lr] = f2bf(accH[qf][nf2][reg] * 8.0f);
        }
    f32x4 accW[2][4] = {};
    #pragma unroll
    for (int ks = 0; ks < 2; ks++){
      #pragma unroll
      for (int nf = 0; nf < 4; nf++){
        int t = nf*16 + lr;
        us8 aw_ = {};
        if (t < 63){
          const float* src = rpw + (size_t)t*64 + ks*32 + lg*8;
          #pragma unroll
          for (int j = 0; j < 8; j++) aw_[j] = f2bf(src[j]);
        }
        #pragma unroll
        for (int qf = 0; qf < 2; qf++) accW[qf][nf] = MFMA16(aw_, aq[qf][ks], accW[qf][nf]);
      }
    }
    #pragma unroll
    for (int qf = 0; qf < 2; qf++)
      #pragma unroll
      for (int nf = 0; nf < 4; nf++)
        #pragma unroll
        for (int reg = 0; reg < 4; reg++){
          int t_out = nf*16 + lg*4 + reg;
          int qw = qf*16 + lr;
          int kw = qw - t_out + 31;
          if (kw >= 0 && kw < 32)
            RWc[kw*128 + w*32 + qf*16 + lr] = f2bf(accW[qf][nf][reg] * 8.0f);
        }
    // preload RW into regs (own-wave LDS region, in-wave ordering suffices)
    #pragma unroll
    for (int qf = 0; qf < 2; qf++)
      #pragma unroll
      for (int hf = 0; hf < 2; hf++)
        #pragma unroll
        for (int reg = 0; reg < 4; reg++)
          rwreg[qf][hf][reg] = bf2f(RWc[(hf*16 + lg*4 + reg)*128 + w*32 + qf*16 + lr]);
  }
  __syncthreads();   // all rwreg reads done before any wave stages into Vs[1]

  f32x4 O[2][4] = {};
  f32x4 lac[2] = {};
  s4 ones4;
  ones4.x = (short)0x3F80; ones4.y = (short)0x3F80; ones4.z = (short)0x3F80; ones4.w = (short)0x3F80;

  for (int kt = 0; kt < 17; kt++){
    int cur = kt & 1;
    if (kt < 16){
      #pragma unroll
      for (int t = 0; t < 2; t++){
        int i = t*256 + tid;
        int row = i >> 3, cs = (i & 7) ^ (row & 7);
        gl_lds16(&kbase[(size_t)((kt+1)*64 + row)*64 + cs*8], &Ks[cur^1][(t*256 + w*64)*8]);
        gl_lds16(&vbase[(size_t)row*NPAD + (kt+1)*64 + cs*8], &Vs[cur^1][(t*256 + w*64)*8]);
      }
      asm volatile("s_waitcnt vmcnt(4)" ::: "memory");
    } else {
      asm volatile("s_waitcnt vmcnt(0)" ::: "memory");
    }
    __builtin_amdgcn_sched_barrier(0);
    __builtin_amdgcn_s_barrier();

    f32x4 S[2][4] = {};
    __builtin_amdgcn_s_setprio(1);
    #pragma unroll
    for (int ks = 0; ks < 2; ks++)
      #pragma unroll
      for (int nf = 0; nf < 4; nf++){
        us8 bk = *reinterpret_cast<const us8*>(
            &Ks[cur][(nf*16 + lr)*64 + (((ks*4 + lg) ^ (lr & 7)) * 8)]);
        S[0][nf] = MFMA16(bk, aq[0][ks], S[0][nf]);
        S[1][nf] = MFMA16(bk, aq[1][ks], S[1][nf]);
      }
    __builtin_amdgcn_s_setprio(0);

    bool gk = (qt < 8) && (kt < 16);
    float rh2[2][2];
    #pragma unroll
    for (int qf = 0; qf < 2; qf++)
      #pragma unroll
      for (int hf = 0; hf < 2; hf++)
        rh2[qf][hf] = gk ? (bf2f(RHt[(kt*2 + hf)*128 + w*32 + qf*16 + lr]) - C2) : -C2;

    s4 pa[2][4];
    #pragma unroll
    for (int qf = 0; qf < 2; qf++){
      #pragma unroll
      for (int nf = 0; nf < 4; nf++){
        float pv[4];
        #pragma unroll
        for (int reg = 0; reg < 4; reg++){
          float logit = S[qf][nf][reg] + rh2[qf][nf>>1] + (gk ? rwreg[qf][nf&1][reg] : 0.f);
          float p = __builtin_amdgcn_exp2f(logit);
          int key = kt*64 + nf*16 + lg*4 + reg;
          pv[reg] = (key < NTOK) ? p : 0.f;
        }
        unsigned int u0 = __builtin_amdgcn_perm(
            __builtin_bit_cast(unsigned int, pv[1]), __builtin_bit_cast(unsigned int, pv[0]), 0x07060302u);
        unsigned int u1 = __builtin_amdgcn_perm(
            __builtin_bit_cast(unsigned int, pv[3]), __builtin_bit_cast(unsigned int, pv[2]), 0x07060302u);
        uint2 uu; uu.x = u0; uu.y = u1;
        pa[qf][nf] = __builtin_bit_cast(s4, uu);
      }
    }

    __builtin_amdgcn_s_setprio(1);
    #pragma unroll
    for (int qf = 0; qf < 2; qf++)
      #pragma unroll
      for (int nf = 0; nf < 4; nf++)
        lac[qf] = MFMAH(pa[qf][nf], ones4, lac[qf]);
    #pragma unroll
    for (int nf = 0; nf < 4; nf++){
      #pragma unroll
      for (int nfd = 0; nfd < 4; nfd++){
        us4 bv = *reinterpret_cast<const us4*>(
            &Vs[cur][(nfd*16 + lr)*64 + (((nf*2 + (lg>>1)) ^ (lr & 7))*8) + (lg&1)*4]);
        O[0][nfd] = MFMAH(pa[0][nf], bv, O[0][nfd]);
        O[1][nfd] = MFMAH(pa[1][nf], bv, O[1][nfd]);
      }
    }
    __builtin_amdgcn_s_setprio(0);
    __builtin_amdgcn_s_barrier();
  }

  #pragma unroll
  for (int qf = 0; qf < 2; qf++)
    #pragma unroll
    for (int reg = 0; reg < 4; reg++){
      int qg = qt*128 + w*32 + qf*16 + lg*4 + reg;
      if (qg < NTOK){
        float inv = 1.0f / lac[qf][reg];
        #pragma unroll
        for (int nfd = 0; nfd < 4; nfd++)
          ao[(size_t)(b_ * NTOK + qg) * 1024 + h*64 + nfd*16 + lr] = f2bf(O[qf][nfd][reg] * inv);
      }
    }
}

// ---------------- proj GEMM: 256x128 tile, 8 waves, counted-vmcnt 2-phase ----------------
__global__ __launch_bounds__(512,4) void proj_gemm(
    const unsigned short* __restrict__ A,   // [MPAD][1024]
    const unsigned short* __restrict__ Bw,  // [1024][1024]
    const float* __restrict__ bias,
    float* __restrict__ out)
{
  const int K = 1024;
  __shared__ __align__(16) unsigned short As[2][256*32];
  __shared__ __align__(16) unsigned short Bs[2][128*32];
  int tid = threadIdx.x;
  int id = blockIdx.x;
  int work = (id & 7) * 33 + (id >> 3);        // 264 = 8 * 33
  int m0 = (work / 8) * 256, n0 = (work % 8) * 128;
  int w = tid >> 6, lane = tid & 63, lr = lane & 15, lg = lane >> 4;
  int wr = w >> 1, wc = w & 1;
  int srow = lane >> 2;
  int scol = ((lane & 3) ^ ((lane >> 3) & 3)) * 8;
  int sa = (lg ^ ((lr >> 1) & 3)) * 8;
  f32x4 acc[4][4] = {};

  auto stage = [&](int buf, int k0){
    gl_lds16(&A [(size_t)(m0 + w*32      + srow) * K + k0 + scol], &As[buf][(w*2  )*512]);
    gl_lds16(&A [(size_t)(m0 + w*32 + 16 + srow) * K + k0 + scol], &As[buf][(w*2+1)*512]);
    gl_lds16(&Bw[(size_t)(n0 + w*16      + srow) * K + k0 + scol], &Bs[buf][ w      *512]);
  };

  stage(0, 0);

  for (int kt = 0; kt < 32; kt++){
    int cur = kt & 1;
    if (kt < 31){
      stage(cur ^ 1, (kt + 1) * 32);
      asm volatile("s_waitcnt vmcnt(3)" ::: "memory");
    } else {
      asm volatile("s_waitcnt vmcnt(0)" ::: "memory");
    }
    __builtin_amdgcn_sched_barrier(0);
    __builtin_amdgcn_s_barrier();

    us8 a[4], b[4];
    #pragma unroll
    for (int mi = 0; mi < 4; mi++) a[mi] = *reinterpret_cast<const us8*>(&As[cur][(wr*64 + mi*16 + lr)*32 + sa]);
    #pragma unroll
    for (int ni = 0; ni < 4; ni++) b[ni] = *reinterpret_cast<const us8*>(&Bs[cur][(wc*64 + ni*16 + lr)*32 + sa]);
    #pragma unroll
    for (int mi = 0; mi < 4; mi++)
      #pragma unroll
      for (int ni = 0; ni < 4; ni++)
        acc[mi][ni] = MFMA16(a[mi], b[ni], acc[mi][ni]);
    __builtin_amdgcn_s_barrier();
  }

  #pragma unroll
  for (int mi = 0; mi < 4; mi++){
    #pragma unroll
    for (int ni = 0; ni < 4; ni++){
      #pragma unroll
      for (int reg = 0; reg < 4; reg++){
        int m = m0 + wr*64 + mi*16 + lg*4 + reg;
        if (m >= MTOT) continue;
        int n = n0 + wc*64 + ni*16 + lr;
        out[(size_t)m * 1024 + n] = acc[mi][ni][reg] + bias[n];
      }
    }
  }
}

extern "C" void kernel_launch(void* const* d_in, const int* in_sizes, int n_in,
                              void* d_out, int out_size, void* d_ws, size_t ws_size,
                              hipStream_t stream)
{
  const float* x      = (const float*)d_in[0];
  const float* qkv_w  = (const float*)d_in[1];
  const float* qkv_b  = (const float*)d_in[2];
  const float* proj_w = (const float*)d_in[3];
  const float* proj_b = (const float*)d_in[4];
  const float* rph    = (const float*)d_in[5];
  const float* rpw    = (const float*)d_in[6];
  float* out = (float*)d_out;

  char* ws = (char*)d_ws;
  size_t off = 0;
  auto alloc = [&](size_t bytes){ char* p = ws + off; off += (bytes + 255) & ~(size_t)255; return p; };
  unsigned short* x_bf  = (unsigned short*)alloc((size_t)MPAD * 1024 * 2);
  unsigned short* qw_bf = (unsigned short*)alloc((size_t)3072 * 1024 * 2);
  unsigned short* pw_bf = (unsigned short*)alloc((size_t)1024 * 1024 * 2);
  unsigned short* qbuf  = (unsigned short*)alloc((size_t)128 * NPAD * 64 * 2);
  unsigned short* kbuf  = (unsigned short*)alloc((size_t)128 * NPAD * 64 * 2);
  unsigned short* vtbuf = (unsigned short*)alloc((size_t)128 * 64 * NPAD * 2);
  unsigned short* aout  = (unsigned short*)alloc((size_t)MPAD * 1024 * 2);
  if (off > ws_size) return;

  // vb (normal-layout V, exactly MTOT*1024*2 B) aliases the live region of aout;
  // consumed by transpose_v before attn writes aout.
  unsigned short* vbuf = aout;

  const int n4x = MTOT * 1024 / 4, n4q = 3072 * 1024 / 4, n4p = 1024 * 1024 / 4;
  int ntot = n4x + n4q + n4p + 128 * (NPAD - NTOK) * 64 + 2 * (MPAD - MTOT) * 1024;
  prep<<<dim3((ntot + 255) / 256), 256, 0, stream>>>(x, qkv_w, proj_w,
                                                     x_bf, qw_bf, pw_bf,
                                                     qbuf, kbuf, aout);

  qkv_gemm<<<dim3(792), 512, 0, stream>>>(x_bf, qw_bf, qkv_b, qbuf, kbuf, vbuf);
  transpose_v<<<dim3(128 * 17), 256, 0, stream>>>(vbuf, vtbuf);
  attn_kernel<<<dim3(1152), 256, 0, stream>>>(qbuf, kbuf, vtbuf, rph, rpw, aout);
  proj_gemm<<<dim3(264), 512, 0, stream>>>(aout, pw_bf, proj_b, out);
}

// Round 12
// 244.506 us; speedup vs baseline: 1.0004x; 1.0004x over previous
//
#include <hip/hip_runtime.h>

#define BATCH 8
#define NTOK 1032
#define NPAD 1152
#define MTOT (BATCH*NTOK)   // 8256
#define MPAD 8448           // 33 * 256

#define SCALE_Q 0.18033688011112042f   // 0.125 * log2(e)
#define C2      5.770780163555854f     // 4 * log2(e)

typedef __bf16 bf16x8 __attribute__((ext_vector_type(8)));
typedef float f32x4 __attribute__((ext_vector_type(4)));
typedef unsigned short us8 __attribute__((ext_vector_type(8)));
typedef unsigned short us4 __attribute__((ext_vector_type(4)));
typedef short s4 __attribute__((ext_vector_type(4)));

__device__ __forceinline__ unsigned short f2bf(float f){
  unsigned int u = __builtin_bit_cast(unsigned int, f);
  u += 0x7fffu + ((u >> 16) & 1u);          // RNE
  return (unsigned short)(u >> 16);
}
__device__ __forceinline__ float bf2f(unsigned short u){
  return __builtin_bit_cast(float, (unsigned int)u << 16);
}

#define MFMA16(a,b,c) __builtin_amdgcn_mfma_f32_16x16x32_bf16( \
    __builtin_bit_cast(bf16x8,(a)), __builtin_bit_cast(bf16x8,(b)), (c), 0, 0, 0)
#define MFMAH(a,b,c) __builtin_amdgcn_mfma_f32_16x16x16bf16_1k( \
    __builtin_bit_cast(s4,(a)), __builtin_bit_cast(s4,(b)), (c), 0, 0, 0)

__device__ __forceinline__ void gl_lds16(const unsigned short* g, unsigned short* l){
  __builtin_amdgcn_global_load_lds(
      (const __attribute__((address_space(1))) unsigned int*)g,
      (__attribute__((address_space(3))) unsigned int*)l, 16, 0, 0);
}

// ---------------- prep: fused fp32->bf16 conversions + pad zeroing ----------------
__global__ __launch_bounds__(256) void prep(
    const float* __restrict__ x, const float* __restrict__ qw, const float* __restrict__ pw,
    unsigned short* __restrict__ x_bf, unsigned short* __restrict__ qw_bf,
    unsigned short* __restrict__ pw_bf,
    unsigned short* __restrict__ qb, unsigned short* __restrict__ kb,
    unsigned short* __restrict__ ao)
{
  int i = blockIdx.x * 256 + threadIdx.x;
  const int n4x = MTOT * 1024 / 4;
  const int n4q = 3072 * 1024 / 4;
  const int n4p = 1024 * 1024 / 4;
  const int c1 = n4x, c2 = c1 + n4q, c3 = c2 + n4p;
  const int t1 = c3 + 128 * (NPAD - NTOK) * 64;
  const int t2 = t1 + (MPAD - MTOT) * 1024;
  const int t3 = t2 + (MPAD - MTOT) * 1024;

  if (i < c3){
    const float* src; unsigned short* dst; int j;
    if (i < c1){ src = x;  dst = x_bf;  j = i; }
    else if (i < c2){ src = qw; dst = qw_bf; j = i - c1; }
    else { src = pw; dst = pw_bf; j = i - c2; }
    float4 v = reinterpret_cast<const float4*>(src)[j];
    us4 o; o.x = f2bf(v.x); o.y = f2bf(v.y); o.z = f2bf(v.z); o.w = f2bf(v.w);
    reinterpret_cast<us4*>(dst)[j] = o;
  } else if (i < t1){
    int j = i - c3;
    int bh = j / ((NPAD - NTOK) * 64);
    int r  = (j / 64) % (NPAD - NTOK);
    int d  = j % 64;
    int idx = (bh * NPAD + NTOK + r) * 64 + d;
    qb[idx] = 0;
    kb[idx] = 0;
  } else if (i < t2){
    x_bf[(size_t)MTOT * 1024 + (i - t1)] = 0;
  } else if (i < t3){
    ao[(size_t)MTOT * 1024 + (i - t2)] = 0;
  }
}

// ---------------- QKV GEMM: 256x128 tile, 8 waves, counted-vmcnt 2-phase, swizzled LDS ----------------
__global__ __launch_bounds__(512,4) void qkv_gemm(
    const unsigned short* __restrict__ A,   // [MPAD][1024] bf16
    const unsigned short* __restrict__ Bw,  // [3072][1024] bf16
    const float* __restrict__ bias,         // [3072]
    unsigned short* __restrict__ qb,        // [128][NPAD][64]  (q pre-scaled by SCALE_Q)
    unsigned short* __restrict__ kb,        // [128][NPAD][64]
    unsigned short* __restrict__ vb)        // [128][NTOK][64]  (normal layout; transposed later)
{
  const int K = 1024;
  __shared__ __align__(16) unsigned short As[2][256*32];   // 16 KB per buf
  __shared__ __align__(16) unsigned short Bs[2][128*32];   // 8 KB per buf
  int tid = threadIdx.x;
  int id = blockIdx.x;
  int work = (id & 7) * 99 + (id >> 3);        // 792 = 8 * 99, bijective
  int m0 = (work / 24) * 256, n0 = (work % 24) * 128;
  int w = tid >> 6, lane = tid & 63, lr = lane & 15, lg = lane >> 4;
  int wr = w >> 1, wc = w & 1;                 // 4M x 2N waves; per-wave 64x64 out
  int srow = lane >> 2;
  int scol = ((lane & 3) ^ ((lane >> 3) & 3)) * 8;   // pre-swizzled source slot
  int sa = (lg ^ ((lr >> 1) & 3)) * 8;               // read-side involution
  f32x4 acc[4][4] = {};

  auto stage = [&](int buf, int k0){
    gl_lds16(&A [(size_t)(m0 + w*32      + srow) * K + k0 + scol], &As[buf][(w*2  )*512]);
    gl_lds16(&A [(size_t)(m0 + w*32 + 16 + srow) * K + k0 + scol], &As[buf][(w*2+1)*512]);
    gl_lds16(&Bw[(size_t)(n0 + w*16      + srow) * K + k0 + scol], &Bs[buf][ w      *512]);
  };

  stage(0, 0);   // prologue: tile 0 in flight (3 loads/wave)

  for (int kt = 0; kt < 32; kt++){
    int cur = kt & 1;
    if (kt < 31){
      stage(cur ^ 1, (kt + 1) * 32);
      asm volatile("s_waitcnt vmcnt(3)" ::: "memory");   // tile kt landed; kt+1 in flight
    } else {
      asm volatile("s_waitcnt vmcnt(0)" ::: "memory");
    }
    __builtin_amdgcn_sched_barrier(0);
    __builtin_amdgcn_s_barrier();                        // tile kt visible to all waves

    us8 a[4], b[4];
    #pragma unroll
    for (int mi = 0; mi < 4; mi++) a[mi] = *reinterpret_cast<const us8*>(&As[cur][(wr*64 + mi*16 + lr)*32 + sa]);
    #pragma unroll
    for (int ni = 0; ni < 4; ni++) b[ni] = *reinterpret_cast<const us8*>(&Bs[cur][(wc*64 + ni*16 + lr)*32 + sa]);
    #pragma unroll
    for (int mi = 0; mi < 4; mi++)
      #pragma unroll
      for (int ni = 0; ni < 4; ni++)
        acc[mi][ni] = MFMA16(a[mi], b[ni], acc[mi][ni]);
    __builtin_amdgcn_s_barrier();                        // reads of cur done; next iter overwrites
  }

  // epilogue: q/k into padded [bh][n][64]; v into normal [bh][n][64]
  #pragma unroll
  for (int mi = 0; mi < 4; mi++){
    #pragma unroll
    for (int ni = 0; ni < 4; ni++){
      #pragma unroll
      for (int reg = 0; reg < 4; reg++){
        int m = m0 + wr*64 + mi*16 + lg*4 + reg;
        if (m >= MTOT) continue;
        int n = n0 + wc*64 + ni*16 + lr;
        float val = acc[mi][ni][reg] + bias[n];
        int b_ = m / NTOK, nidx = m % NTOK;
        int t = n >> 10, h = (n >> 6) & 15, d = n & 63;
        int bh = h * BATCH + b_;
        if (t == 0){
          qb[(size_t)(bh * NPAD + nidx) * 64 + d] = f2bf(val * SCALE_Q);
        } else if (t == 1){
          kb[(size_t)(bh * NPAD + nidx) * 64 + d] = f2bf(val);
        } else {
          vb[(size_t)(bh * NTOK + nidx) * 64 + d] = f2bf(val);
        }
      }
    }
  }
}

// ---------------- V transpose: vb [bh][n][64] -> vt [bh][64][NPAD] ----------------
__global__ __launch_bounds__(256) void transpose_v(const unsigned short* __restrict__ vb,
                                                   unsigned short* __restrict__ vt){
  __shared__ unsigned short Ls[64][72];
  int blk = blockIdx.x;
  int bh = blk / 17, tl = blk % 17;
  int n0 = tl * 64;
  int t = threadIdx.x;

  #pragma unroll
  for (int p = 0; p < 2; p++){
    int idx = p * 256 + t;
    int r = idx >> 3, c = idx & 7;
    us8 v = {};
    if (n0 + r < NTOK)
      v = *reinterpret_cast<const us8*>(&vb[((size_t)bh * NTOK + n0 + r) * 64 + c * 8]);
    *reinterpret_cast<us8*>(&Ls[r][c * 8]) = v;
  }
  __syncthreads();

  int d = t & 63, ng = t >> 6;
  us8 o[2];
  #pragma unroll
  for (int hf = 0; hf < 2; hf++){
    #pragma unroll
    for (int j = 0; j < 8; j++) o[hf][j] = Ls[ng*16 + hf*8 + j][d];
    *reinterpret_cast<us8*>(&vt[((size_t)bh * 64 + d) * NPAD + n0 + ng*16 + hf*8]) = o[hf];
  }
}

// ---------------- flash attention v7: v6 with RWc overlaid on Vs[1] (LDS 48->40KB, 4 blocks/CU) ----------------
__global__ __launch_bounds__(256,4) void attn_kernel(
    const unsigned short* __restrict__ qb,
    const unsigned short* __restrict__ kb,
    const unsigned short* __restrict__ vt,
    const float* __restrict__ rph,   // [63][64]
    const float* __restrict__ rpw,   // [63][64]
    unsigned short* __restrict__ ao) // [MPAD][1024], rows b*NTOK+n
{
  __shared__ __align__(16) unsigned short Ks[2][64*64];   // 16 KB
  __shared__ __align__(16) unsigned short Vs[2][64*64];   // 16 KB
  __shared__ unsigned short RHt[32*128];                  // 8 KB, persistent
  // RWc is transient (consumed into rwreg before the K-loop): overlay on Vs[1],
  // which is first written by iter-0's stage — issued after the __syncthreads below.
  unsigned short* RWc = &Vs[1][0];                        // 8 KB scratch, no extra LDS

  int id = blockIdx.x;
  int work = (id & 7) * 144 + (id >> 3);
  int bh = work / 9;
  int qt = work % 9;
  int tid = threadIdx.x, w = tid >> 6, lane = tid & 63, lr = lane & 15, lg = lane >> 4;
  int h = bh >> 3, b_ = bh & 7;

  const unsigned short* qbase = qb + (size_t)bh * NPAD * 64;
  const unsigned short* kbase = kb + (size_t)bh * NPAD * 64;
  const unsigned short* vbase = vt + (size_t)bh * 64 * NPAD;

  // stage kt=0 into buf 0 only (Vs[1] still scratch)
  #pragma unroll
  for (int t = 0; t < 2; t++){
    int i = t*256 + tid;
    int row = i >> 3, cs = (i & 7) ^ (row & 7);
    gl_lds16(&kbase[(size_t)row*64 + cs*8],   &Ks[0][(t*256 + w*64)*8]);
    gl_lds16(&vbase[(size_t)row*NPAD + cs*8], &Vs[0][(t*256 + w*64)*8]);
  }

  us8 aq[2][2];
  #pragma unroll
  for (int qf = 0; qf < 2; qf++){
    int qrow = qt*128 + w*32 + qf*16 + lr;
    aq[qf][0] = *reinterpret_cast<const us8*>(&qbase[(size_t)qrow*64 + lg*8]);
    aq[qf][1] = *reinterpret_cast<const us8*>(&qbase[(size_t)qrow*64 + 32 + lg*8]);
  }

  float rwreg[2][2][4] = {};

  if (qt < 8){
    int qh = qt*4 + w;
    f32x4 accH[2][2] = {};
    #pragma unroll
    for (int ks = 0; ks < 2; ks++){
      #pragma unroll
      for (int nf2 = 0; nf2 < 2; nf2++){
        int t = nf2*16 + lr;
        const float* src = rph + (size_t)(qh - t + 31)*64 + ks*32 + lg*8;
        us8 ar;
        #pragma unroll
        for (int j = 0; j < 8; j++) ar[j] = f2bf(src[j]);
        #pragma unroll
        for (int qf = 0; qf < 2; qf++) accH[qf][nf2] = MFMA16(ar, aq[qf][ks], accH[qf][nf2]);
      }
    }
    #pragma unroll
    for (int qf = 0; qf < 2; qf++)
      #pragma unroll
      for (int nf2 = 0; nf2 < 2; nf2++)
        #pragma unroll
        for (int reg = 0; reg < 4; reg++){
          int t_out = nf2*16 + lg*4 + reg;
          RHt[t_out*128 + w*32 + qf*16 + lr] = f2bf(accH[qf][nf2][reg] * 8.0f);
        }
    f32x4 accW[2][4] = {};
    #pragma unroll
    for (int ks = 0; ks < 2; ks++){
      #pragma unroll
      for (int nf = 0; nf < 4; nf++){
        int t = nf*16 + lr;
        us8 aw_ = {};
        if (t < 63){
          const float* src = rpw + (size_t)t*64 + ks*32 + lg*8;
          #pragma unroll
          for (int j = 0; j < 8; j++) aw_[j] = f2bf(src[j]);
        }
        #pragma unroll
        for (int qf = 0; qf < 2; qf++) accW[qf][nf] = MFMA16(aw_, aq[qf][ks], accW[qf][nf]);
      }
    }
    #pragma unroll
    for (int qf = 0; qf < 2; qf++)
      #pragma unroll
      for (int nf = 0; nf < 4; nf++)
        #pragma unroll
        for (int reg = 0; reg < 4; reg++){
          int t_out = nf*16 + lg*4 + reg;
          int qw = qf*16 + lr;
          int kw = qw - t_out + 31;
          if (kw >= 0 && kw < 32)
            RWc[kw*128 + w*32 + qf*16 + lr] = f2bf(accW[qf][nf][reg] * 8.0f);
        }
    // preload RW into regs (own-wave LDS region, in-wave ordering suffices)
    #pragma unroll
    for (int qf = 0; qf < 2; qf++)
      #pragma unroll
      for (int hf = 0; hf < 2; hf++)
        #pragma unroll
        for (int reg = 0; reg < 4; reg++)
          rwreg[qf][hf][reg] = bf2f(RWc[(hf*16 + lg*4 + reg)*128 + w*32 + qf*16 + lr]);
  }
  __syncthreads();   // all rwreg reads done before any wave stages into Vs[1]

  f32x4 O[2][4] = {};
  f32x4 lac[2] = {};
  s4 ones4;
  ones4.x = (short)0x3F80; ones4.y = (short)0x3F80; ones4.z = (short)0x3F80; ones4.w = (short)0x3F80;

  for (int kt = 0; kt < 17; kt++){
    int cur = kt & 1;
    if (kt < 16){
      #pragma unroll
      for (int t = 0; t < 2; t++){
        int i = t*256 + tid;
        int row = i >> 3, cs = (i & 7) ^ (row & 7);
        gl_lds16(&kbase[(size_t)((kt+1)*64 + row)*64 + cs*8], &Ks[cur^1][(t*256 + w*64)*8]);
        gl_lds16(&vbase[(size_t)row*NPAD + (kt+1)*64 + cs*8], &Vs[cur^1][(t*256 + w*64)*8]);
      }
      asm volatile("s_waitcnt vmcnt(4)" ::: "memory");
    } else {
      asm volatile("s_waitcnt vmcnt(0)" ::: "memory");
    }
    __builtin_amdgcn_sched_barrier(0);
    __builtin_amdgcn_s_barrier();

    f32x4 S[2][4] = {};
    __builtin_amdgcn_s_setprio(1);
    #pragma unroll
    for (int ks = 0; ks < 2; ks++)
      #pragma unroll
      for (int nf = 0; nf < 4; nf++){
        us8 bk = *reinterpret_cast<const us8*>(
            &Ks[cur][(nf*16 + lr)*64 + (((ks*4 + lg) ^ (lr & 7)) * 8)]);
        S[0][nf] = MFMA16(bk, aq[0][ks], S[0][nf]);
        S[1][nf] = MFMA16(bk, aq[1][ks], S[1][nf]);
      }
    __builtin_amdgcn_s_setprio(0);

    bool gk = (qt < 8) && (kt < 16);
    float rh2[2][2];
    #pragma unroll
    for (int qf = 0; qf < 2; qf++)
      #pragma unroll
      for (int hf = 0; hf < 2; hf++)
        rh2[qf][hf] = gk ? (bf2f(RHt[(kt*2 + hf)*128 + w*32 + qf*16 + lr]) - C2) : -C2;

    s4 pa[2][4];
    #pragma unroll
    for (int qf = 0; qf < 2; qf++){
      #pragma unroll
      for (int nf = 0; nf < 4; nf++){
        float pv[4];
        #pragma unroll
        for (int reg = 0; reg < 4; reg++){
          float logit = S[qf][nf][reg] + rh2[qf][nf>>1] + (gk ? rwreg[qf][nf&1][reg] : 0.f);
          float p = __builtin_amdgcn_exp2f(logit);
          int key = kt*64 + nf*16 + lg*4 + reg;
          pv[reg] = (key < NTOK) ? p : 0.f;
        }
        unsigned int u0 = __builtin_amdgcn_perm(
            __builtin_bit_cast(unsigned int, pv[1]), __builtin_bit_cast(unsigned int, pv[0]), 0x07060302u);
        unsigned int u1 = __builtin_amdgcn_perm(
            __builtin_bit_cast(unsigned int, pv[3]), __builtin_bit_cast(unsigned int, pv[2]), 0x07060302u);
        uint2 uu; uu.x = u0; uu.y = u1;
        pa[qf][nf] = __builtin_bit_cast(s4, uu);
      }
    }

    __builtin_amdgcn_s_setprio(1);
    #pragma unroll
    for (int qf = 0; qf < 2; qf++)
      #pragma unroll
      for (int nf = 0; nf < 4; nf++)
        lac[qf] = MFMAH(pa[qf][nf], ones4, lac[qf]);
    #pragma unroll
    for (int nf = 0; nf < 4; nf++){
      #pragma unroll
      for (int nfd = 0; nfd < 4; nfd++){
        us4 bv = *reinterpret_cast<const us4*>(
            &Vs[cur][(nfd*16 + lr)*64 + (((nf*2 + (lg>>1)) ^ (lr & 7))*8) + (lg&1)*4]);
        O[0][nfd] = MFMAH(pa[0][nf], bv, O[0][nfd]);
        O[1][nfd] = MFMAH(pa[1][nf], bv, O[1][nfd]);
      }
    }
    __builtin_amdgcn_s_setprio(0);
    __builtin_amdgcn_s_barrier();
  }

  #pragma unroll
  for (int qf = 0; qf < 2; qf++)
    #pragma unroll
    for (int reg = 0; reg < 4; reg++){
      int qg = qt*128 + w*32 + qf*16 + lg*4 + reg;
      if (qg < NTOK){
        float inv = 1.0f / lac[qf][reg];
        #pragma unroll
        for (int nfd = 0; nfd < 4; nfd++)
          ao[(size_t)(b_ * NTOK + qg) * 1024 + h*64 + nfd*16 + lr] = f2bf(O[qf][nfd][reg] * inv);
      }
    }
}

// ---------------- proj GEMM: 256x128 tile, 8 waves, counted-vmcnt 2-phase ----------------
__global__ __launch_bounds__(512,4) void proj_gemm(
    const unsigned short* __restrict__ A,   // [MPAD][1024]
    const unsigned short* __restrict__ Bw,  // [1024][1024]
    const float* __restrict__ bias,
    float* __restrict__ out)
{
  const int K = 1024;
  __shared__ __align__(16) unsigned short As[2][256*32];
  __shared__ __align__(16) unsigned short Bs[2][128*32];
  int tid = threadIdx.x;
  int id = blockIdx.x;
  int work = (id & 7) * 33 + (id >> 3);        // 264 = 8 * 33
  int m0 = (work / 8) * 256, n0 = (work % 8) * 128;
  int w = tid >> 6, lane = tid & 63, lr = lane & 15, lg = lane >> 4;
  int wr = w >> 1, wc = w & 1;
  int srow = lane >> 2;
  int scol = ((lane & 3) ^ ((lane >> 3) & 3)) * 8;
  int sa = (lg ^ ((lr >> 1) & 3)) * 8;
  f32x4 acc[4][4] = {};

  auto stage = [&](int buf, int k0){
    gl_lds16(&A [(size_t)(m0 + w*32      + srow) * K + k0 + scol], &As[buf][(w*2  )*512]);
    gl_lds16(&A [(size_t)(m0 + w*32 + 16 + srow) * K + k0 + scol], &As[buf][(w*2+1)*512]);
    gl_lds16(&Bw[(size_t)(n0 + w*16      + srow) * K + k0 + scol], &Bs[buf][ w      *512]);
  };

  stage(0, 0);

  for (int kt = 0; kt < 32; kt++){
    int cur = kt & 1;
    if (kt < 31){
      stage(cur ^ 1, (kt + 1) * 32);
      asm volatile("s_waitcnt vmcnt(3)" ::: "memory");
    } else {
      asm volatile("s_waitcnt vmcnt(0)" ::: "memory");
    }
    __builtin_amdgcn_sched_barrier(0);
    __builtin_amdgcn_s_barrier();

    us8 a[4], b[4];
    #pragma unroll
    for (int mi = 0; mi < 4; mi++) a[mi] = *reinterpret_cast<const us8*>(&As[cur][(wr*64 + mi*16 + lr)*32 + sa]);
    #pragma unroll
    for (int ni = 0; ni < 4; ni++) b[ni] = *reinterpret_cast<const us8*>(&Bs[cur][(wc*64 + ni*16 + lr)*32 + sa]);
    #pragma unroll
    for (int mi = 0; mi < 4; mi++)
      #pragma unroll
      for (int ni = 0; ni < 4; ni++)
        acc[mi][ni] = MFMA16(a[mi], b[ni], acc[mi][ni]);
    __builtin_amdgcn_s_barrier();
  }

  #pragma unroll
  for (int mi = 0; mi < 4; mi++){
    #pragma unroll
    for (int ni = 0; ni < 4; ni++){
      #pragma unroll
      for (int reg = 0; reg < 4; reg++){
        int m = m0 + wr*64 + mi*16 + lg*4 + reg;
        if (m >= MTOT) continue;
        int n = n0 + wc*64 + ni*16 + lr;
        out[(size_t)m * 1024 + n] = acc[mi][ni][reg] + bias[n];
      }
    }
  }
}

extern "C" void kernel_launch(void* const* d_in, const int* in_sizes, int n_in,
                              void* d_out, int out_size, void* d_ws, size_t ws_size,
                              hipStream_t stream)
{
  const float* x      = (const float*)d_in[0];
  const float* qkv_w  = (const float*)d_in[1];
  const float* qkv_b  = (const float*)d_in[2];
  const float* proj_w = (const float*)d_in[3];
  const float* proj_b = (const float*)d_in[4];
  const float* rph    = (const float*)d_in[5];
  const float* rpw    = (const float*)d_in[6];
  float* out = (float*)d_out;

  char* ws = (char*)d_ws;
  size_t off = 0;
  auto alloc = [&](size_t bytes){ char* p = ws + off; off += (bytes + 255) & ~(size_t)255; return p; };
  unsigned short* x_bf  = (unsigned short*)alloc((size_t)MPAD * 1024 * 2);
  unsigned short* qw_bf = (unsigned short*)alloc((size_t)3072 * 1024 * 2);
  unsigned short* pw_bf = (unsigned short*)alloc((size_t)1024 * 1024 * 2);
  unsigned short* qbuf  = (unsigned short*)alloc((size_t)128 * NPAD * 64 * 2);
  unsigned short* kbuf  = (unsigned short*)alloc((size_t)128 * NPAD * 64 * 2);
  unsigned short* vtbuf = (unsigned short*)alloc((size_t)128 * 64 * NPAD * 2);
  unsigned short* aout  = (unsigned short*)alloc((size_t)MPAD * 1024 * 2);
  if (off > ws_size) return;

  // vb (normal-layout V, exactly MTOT*1024*2 B) aliases the live region of aout;
  // consumed by transpose_v before attn writes aout.
  unsigned short* vbuf = aout;

  const int n4x = MTOT * 1024 / 4, n4q = 3072 * 1024 / 4, n4p = 1024 * 1024 / 4;
  int ntot = n4x + n4q + n4p + 128 * (NPAD - NTOK) * 64 + 2 * (MPAD - MTOT) * 1024;
  prep<<<dim3((ntot + 255) / 256), 256, 0, stream>>>(x, qkv_w, proj_w,
                                                     x_bf, qw_bf, pw_bf,
                                                     qbuf, kbuf, aout);

  qkv_gemm<<<dim3(792), 512, 0, stream>>>(x_bf, qw_bf, qkv_b, qbuf, kbuf, vbuf);
  transpose_v<<<dim3(128 * 17), 256, 0, stream>>>(vbuf, vtbuf);
  attn_kernel<<<dim3(1152), 256, 0, stream>>>(qbuf, kbuf, vtbuf, rph, rpw, aout);
  proj_gemm<<<dim3(264), 512, 0, stream>>>(aout, pw_bf, proj_b, out);
}

// Round 13
// 225.319 us; speedup vs baseline: 1.0856x; 1.0852x over previous
//
#include <hip/hip_runtime.h>

#define BATCH 8
#define NTOK 1032
#define NPAD 1152
#define MTOT (BATCH*NTOK)   // 8256
#define MPAD 8448           // 33 * 256

#define SCALE_Q 0.18033688011112042f   // 0.125 * log2(e)
#define C2      5.770780163555854f     // 4 * log2(e)

typedef __bf16 bf16x8 __attribute__((ext_vector_type(8)));
typedef float f32x4 __attribute__((ext_vector_type(4)));
typedef unsigned short us8 __attribute__((ext_vector_type(8)));
typedef unsigned short us4 __attribute__((ext_vector_type(4)));
typedef short s4 __attribute__((ext_vector_type(4)));

__device__ __forceinline__ unsigned short f2bf(float f){
  unsigned int u = __builtin_bit_cast(unsigned int, f);
  u += 0x7fffu + ((u >> 16) & 1u);          // RNE
  return (unsigned short)(u >> 16);
}
__device__ __forceinline__ float bf2f(unsigned short u){
  return __builtin_bit_cast(float, (unsigned int)u << 16);
}

#define MFMA16(a,b,c) __builtin_amdgcn_mfma_f32_16x16x32_bf16( \
    __builtin_bit_cast(bf16x8,(a)), __builtin_bit_cast(bf16x8,(b)), (c), 0, 0, 0)
#define MFMAH(a,b,c) __builtin_amdgcn_mfma_f32_16x16x16bf16_1k( \
    __builtin_bit_cast(s4,(a)), __builtin_bit_cast(s4,(b)), (c), 0, 0, 0)

__device__ __forceinline__ void gl_lds16(const unsigned short* g, unsigned short* l){
  __builtin_amdgcn_global_load_lds(
      (const __attribute__((address_space(1))) unsigned int*)g,
      (__attribute__((address_space(3))) unsigned int*)l, 16, 0, 0);
}

// ---------------- prep: fused fp32->bf16 conversions + pad zeroing ----------------
__global__ __launch_bounds__(256) void prep(
    const float* __restrict__ x, const float* __restrict__ qw, const float* __restrict__ pw,
    unsigned short* __restrict__ x_bf, unsigned short* __restrict__ qw_bf,
    unsigned short* __restrict__ pw_bf,
    unsigned short* __restrict__ qb, unsigned short* __restrict__ kb,
    unsigned short* __restrict__ ao)
{
  int i = blockIdx.x * 256 + threadIdx.x;
  const int n4x = MTOT * 1024 / 4;
  const int n4q = 3072 * 1024 / 4;
  const int n4p = 1024 * 1024 / 4;
  const int c1 = n4x, c2 = c1 + n4q, c3 = c2 + n4p;
  const int t1 = c3 + 128 * (NPAD - NTOK) * 64;
  const int t2 = t1 + (MPAD - MTOT) * 1024;
  const int t3 = t2 + (MPAD - MTOT) * 1024;

  if (i < c3){
    const float* src; unsigned short* dst; int j;
    if (i < c1){ src = x;  dst = x_bf;  j = i; }
    else if (i < c2){ src = qw; dst = qw_bf; j = i - c1; }
    else { src = pw; dst = pw_bf; j = i - c2; }
    float4 v = reinterpret_cast<const float4*>(src)[j];
    us4 o; o.x = f2bf(v.x); o.y = f2bf(v.y); o.z = f2bf(v.z); o.w = f2bf(v.w);
    reinterpret_cast<us4*>(dst)[j] = o;
  } else if (i < t1){
    int j = i - c3;
    int bh = j / ((NPAD - NTOK) * 64);
    int r  = (j / 64) % (NPAD - NTOK);
    int d  = j % 64;
    int idx = (bh * NPAD + NTOK + r) * 64 + d;
    qb[idx] = 0;
    kb[idx] = 0;
  } else if (i < t2){
    x_bf[(size_t)MTOT * 1024 + (i - t1)] = 0;
  } else if (i < t3){
    ao[(size_t)MTOT * 1024 + (i - t2)] = 0;
  }
}

// ---------------- QKV GEMM: 256x128 tile, 8 waves, counted-vmcnt 2-phase, swizzled LDS ----------------
__global__ __launch_bounds__(512,4) void qkv_gemm(
    const unsigned short* __restrict__ A,   // [MPAD][1024] bf16
    const unsigned short* __restrict__ Bw,  // [3072][1024] bf16
    const float* __restrict__ bias,         // [3072]
    unsigned short* __restrict__ qb,        // [128][NPAD][64]  (q pre-scaled by SCALE_Q)
    unsigned short* __restrict__ kb,        // [128][NPAD][64]
    unsigned short* __restrict__ vb)        // [128][NTOK][64]  (normal layout; transposed later)
{
  const int K = 1024;
  __shared__ __align__(16) unsigned short As[2][256*32];   // 16 KB per buf
  __shared__ __align__(16) unsigned short Bs[2][128*32];   // 8 KB per buf
  int tid = threadIdx.x;
  int id = blockIdx.x;
  int work = (id & 7) * 99 + (id >> 3);        // 792 = 8 * 99, bijective
  int m0 = (work / 24) * 256, n0 = (work % 24) * 128;
  int w = tid >> 6, lane = tid & 63, lr = lane & 15, lg = lane >> 4;
  int wr = w >> 1, wc = w & 1;                 // 4M x 2N waves; per-wave 64x64 out
  int srow = lane >> 2;
  int scol = ((lane & 3) ^ ((lane >> 3) & 3)) * 8;   // pre-swizzled source slot
  int sa = (lg ^ ((lr >> 1) & 3)) * 8;               // read-side involution
  f32x4 acc[4][4] = {};

  auto stage = [&](int buf, int k0){
    gl_lds16(&A [(size_t)(m0 + w*32      + srow) * K + k0 + scol], &As[buf][(w*2  )*512]);
    gl_lds16(&A [(size_t)(m0 + w*32 + 16 + srow) * K + k0 + scol], &As[buf][(w*2+1)*512]);
    gl_lds16(&Bw[(size_t)(n0 + w*16      + srow) * K + k0 + scol], &Bs[buf][ w      *512]);
  };

  stage(0, 0);   // prologue: tile 0 in flight (3 loads/wave)

  for (int kt = 0; kt < 32; kt++){
    int cur = kt & 1;
    if (kt < 31){
      stage(cur ^ 1, (kt + 1) * 32);
      asm volatile("s_waitcnt vmcnt(3)" ::: "memory");   // tile kt landed; kt+1 in flight
    } else {
      asm volatile("s_waitcnt vmcnt(0)" ::: "memory");
    }
    __builtin_amdgcn_sched_barrier(0);
    __builtin_amdgcn_s_barrier();                        // tile kt visible to all waves

    us8 a[4], b[4];
    #pragma unroll
    for (int mi = 0; mi < 4; mi++) a[mi] = *reinterpret_cast<const us8*>(&As[cur][(wr*64 + mi*16 + lr)*32 + sa]);
    #pragma unroll
    for (int ni = 0; ni < 4; ni++) b[ni] = *reinterpret_cast<const us8*>(&Bs[cur][(wc*64 + ni*16 + lr)*32 + sa]);
    #pragma unroll
    for (int mi = 0; mi < 4; mi++)
      #pragma unroll
      for (int ni = 0; ni < 4; ni++)
        acc[mi][ni] = MFMA16(a[mi], b[ni], acc[mi][ni]);
    __builtin_amdgcn_s_barrier();                        // reads of cur done; next iter overwrites
  }

  // epilogue: q/k into padded [bh][n][64]; v into normal [bh][n][64]
  #pragma unroll
  for (int mi = 0; mi < 4; mi++){
    #pragma unroll
    for (int ni = 0; ni < 4; ni++){
      #pragma unroll
      for (int reg = 0; reg < 4; reg++){
        int m = m0 + wr*64 + mi*16 + lg*4 + reg;
        if (m >= MTOT) continue;
        int n = n0 + wc*64 + ni*16 + lr;
        float val = acc[mi][ni][reg] + bias[n];
        int b_ = m / NTOK, nidx = m % NTOK;
        int t = n >> 10, h = (n >> 6) & 15, d = n & 63;
        int bh = h * BATCH + b_;
        if (t == 0){
          qb[(size_t)(bh * NPAD + nidx) * 64 + d] = f2bf(val * SCALE_Q);
        } else if (t == 1){
          kb[(size_t)(bh * NPAD + nidx) * 64 + d] = f2bf(val);
        } else {
          vb[(size_t)(bh * NTOK + nidx) * 64 + d] = f2bf(val);
        }
      }
    }
  }
}

// ---------------- V transpose: vb [bh][n][64] -> vt [bh][64][NPAD] ----------------
__global__ __launch_bounds__(256) void transpose_v(const unsigned short* __restrict__ vb,
                                                   unsigned short* __restrict__ vt){
  __shared__ unsigned short Ls[64][72];
  int blk = blockIdx.x;
  int bh = blk / 17, tl = blk % 17;
  int n0 = tl * 64;
  int t = threadIdx.x;

  #pragma unroll
  for (int p = 0; p < 2; p++){
    int idx = p * 256 + t;
    int r = idx >> 3, c = idx & 7;
    us8 v = {};
    if (n0 + r < NTOK)
      v = *reinterpret_cast<const us8*>(&vb[((size_t)bh * NTOK + n0 + r) * 64 + c * 8]);
    *reinterpret_cast<us8*>(&Ls[r][c * 8]) = v;
  }
  __syncthreads();

  int d = t & 63, ng = t >> 6;
  us8 o[2];
  #pragma unroll
  for (int hf = 0; hf < 2; hf++){
    #pragma unroll
    for (int j = 0; j < 8; j++) o[hf][j] = Ls[ng*16 + hf*8 + j][d];
    *reinterpret_cast<us8*>(&vt[((size_t)bh * 64 + d) * NPAD + n0 + ng*16 + hf*8]) = o[hf];
  }
}

// ---------------- flash attention v8: RWc overlay kept, launch bound relaxed to 3 ----------------
__global__ __launch_bounds__(256,3) void attn_kernel(
    const unsigned short* __restrict__ qb,
    const unsigned short* __restrict__ kb,
    const unsigned short* __restrict__ vt,
    const float* __restrict__ rph,   // [63][64]
    const float* __restrict__ rpw,   // [63][64]
    unsigned short* __restrict__ ao) // [MPAD][1024], rows b*NTOK+n
{
  __shared__ __align__(16) unsigned short Ks[2][64*64];   // 16 KB
  __shared__ __align__(16) unsigned short Vs[2][64*64];   // 16 KB
  __shared__ unsigned short RHt[32*128];                  // 8 KB, persistent
  // RWc is transient (consumed into rwreg before the K-loop): overlay on Vs[1],
  // which is first written by iter-0's stage — issued after the __syncthreads below.
  unsigned short* RWc = &Vs[1][0];                        // 8 KB scratch, no extra LDS

  int id = blockIdx.x;
  int work = (id & 7) * 144 + (id >> 3);
  int bh = work / 9;
  int qt = work % 9;
  int tid = threadIdx.x, w = tid >> 6, lane = tid & 63, lr = lane & 15, lg = lane >> 4;
  int h = bh >> 3, b_ = bh & 7;

  const unsigned short* qbase = qb + (size_t)bh * NPAD * 64;
  const unsigned short* kbase = kb + (size_t)bh * NPAD * 64;
  const unsigned short* vbase = vt + (size_t)bh * 64 * NPAD;

  // stage kt=0 into buf 0 only (Vs[1] still scratch)
  #pragma unroll
  for (int t = 0; t < 2; t++){
    int i = t*256 + tid;
    int row = i >> 3, cs = (i & 7) ^ (row & 7);
    gl_lds16(&kbase[(size_t)row*64 + cs*8],   &Ks[0][(t*256 + w*64)*8]);
    gl_lds16(&vbase[(size_t)row*NPAD + cs*8], &Vs[0][(t*256 + w*64)*8]);
  }

  us8 aq[2][2];
  #pragma unroll
  for (int qf = 0; qf < 2; qf++){
    int qrow = qt*128 + w*32 + qf*16 + lr;
    aq[qf][0] = *reinterpret_cast<const us8*>(&qbase[(size_t)qrow*64 + lg*8]);
    aq[qf][1] = *reinterpret_cast<const us8*>(&qbase[(size_t)qrow*64 + 32 + lg*8]);
  }

  float rwreg[2][2][4] = {};

  if (qt < 8){
    int qh = qt*4 + w;
    f32x4 accH[2][2] = {};
    #pragma unroll
    for (int ks = 0; ks < 2; ks++){
      #pragma unroll
      for (int nf2 = 0; nf2 < 2; nf2++){
        int t = nf2*16 + lr;
        const float* src = rph + (size_t)(qh - t + 31)*64 + ks*32 + lg*8;
        us8 ar;
        #pragma unroll
        for (int j = 0; j < 8; j++) ar[j] = f2bf(src[j]);
        #pragma unroll
        for (int qf = 0; qf < 2; qf++) accH[qf][nf2] = MFMA16(ar, aq[qf][ks], accH[qf][nf2]);
      }
    }
    #pragma unroll
    for (int qf = 0; qf < 2; qf++)
      #pragma unroll
      for (int nf2 = 0; nf2 < 2; nf2++)
        #pragma unroll
        for (int reg = 0; reg < 4; reg++){
          int t_out = nf2*16 + lg*4 + reg;
          RHt[t_out*128 + w*32 + qf*16 + lr] = f2bf(accH[qf][nf2][reg] * 8.0f);
        }
    f32x4 accW[2][4] = {};
    #pragma unroll
    for (int ks = 0; ks < 2; ks++){
      #pragma unroll
      for (int nf = 0; nf < 4; nf++){
        int t = nf*16 + lr;
        us8 aw_ = {};
        if (t < 63){
          const float* src = rpw + (size_t)t*64 + ks*32 + lg*8;
          #pragma unroll
          for (int j = 0; j < 8; j++) aw_[j] = f2bf(src[j]);
        }
        #pragma unroll
        for (int qf = 0; qf < 2; qf++) accW[qf][nf] = MFMA16(aw_, aq[qf][ks], accW[qf][nf]);
      }
    }
    #pragma unroll
    for (int qf = 0; qf < 2; qf++)
      #pragma unroll
      for (int nf = 0; nf < 4; nf++)
        #pragma unroll
        for (int reg = 0; reg < 4; reg++){
          int t_out = nf*16 + lg*4 + reg;
          int qw = qf*16 + lr;
          int kw = qw - t_out + 31;
          if (kw >= 0 && kw < 32)
            RWc[kw*128 + w*32 + qf*16 + lr] = f2bf(accW[qf][nf][reg] * 8.0f);
        }
    // preload RW into regs (own-wave LDS region, in-wave ordering suffices)
    #pragma unroll
    for (int qf = 0; qf < 2; qf++)
      #pragma unroll
      for (int hf = 0; hf < 2; hf++)
        #pragma unroll
        for (int reg = 0; reg < 4; reg++)
          rwreg[qf][hf][reg] = bf2f(RWc[(hf*16 + lg*4 + reg)*128 + w*32 + qf*16 + lr]);
  }
  __syncthreads();   // all rwreg reads done before any wave stages into Vs[1]

  f32x4 O[2][4] = {};
  f32x4 lac[2] = {};
  s4 ones4;
  ones4.x = (short)0x3F80; ones4.y = (short)0x3F80; ones4.z = (short)0x3F80; ones4.w = (short)0x3F80;

  for (int kt = 0; kt < 17; kt++){
    int cur = kt & 1;
    if (kt < 16){
      #pragma unroll
      for (int t = 0; t < 2; t++){
        int i = t*256 + tid;
        int row = i >> 3, cs = (i & 7) ^ (row & 7);
        gl_lds16(&kbase[(size_t)((kt+1)*64 + row)*64 + cs*8], &Ks[cur^1][(t*256 + w*64)*8]);
        gl_lds16(&vbase[(size_t)row*NPAD + (kt+1)*64 + cs*8], &Vs[cur^1][(t*256 + w*64)*8]);
      }
      asm volatile("s_waitcnt vmcnt(4)" ::: "memory");
    } else {
      asm volatile("s_waitcnt vmcnt(0)" ::: "memory");
    }
    __builtin_amdgcn_sched_barrier(0);
    __builtin_amdgcn_s_barrier();

    f32x4 S[2][4] = {};
    __builtin_amdgcn_s_setprio(1);
    #pragma unroll
    for (int ks = 0; ks < 2; ks++)
      #pragma unroll
      for (int nf = 0; nf < 4; nf++){
        us8 bk = *reinterpret_cast<const us8*>(
            &Ks[cur][(nf*16 + lr)*64 + (((ks*4 + lg) ^ (lr & 7)) * 8)]);
        S[0][nf] = MFMA16(bk, aq[0][ks], S[0][nf]);
        S[1][nf] = MFMA16(bk, aq[1][ks], S[1][nf]);
      }
    __builtin_amdgcn_s_setprio(0);

    bool gk = (qt < 8) && (kt < 16);
    float rh2[2][2];
    #pragma unroll
    for (int qf = 0; qf < 2; qf++)
      #pragma unroll
      for (int hf = 0; hf < 2; hf++)
        rh2[qf][hf] = gk ? (bf2f(RHt[(kt*2 + hf)*128 + w*32 + qf*16 + lr]) - C2) : -C2;

    s4 pa[2][4];
    #pragma unroll
    for (int qf = 0; qf < 2; qf++){
      #pragma unroll
      for (int nf = 0; nf < 4; nf++){
        float pv[4];
        #pragma unroll
        for (int reg = 0; reg < 4; reg++){
          float logit = S[qf][nf][reg] + rh2[qf][nf>>1] + (gk ? rwreg[qf][nf&1][reg] : 0.f);
          float p = __builtin_amdgcn_exp2f(logit);
          int key = kt*64 + nf*16 + lg*4 + reg;
          pv[reg] = (key < NTOK) ? p : 0.f;
        }
        unsigned int u0 = __builtin_amdgcn_perm(
            __builtin_bit_cast(unsigned int, pv[1]), __builtin_bit_cast(unsigned int, pv[0]), 0x07060302u);
        unsigned int u1 = __builtin_amdgcn_perm(
            __builtin_bit_cast(unsigned int, pv[3]), __builtin_bit_cast(unsigned int, pv[2]), 0x07060302u);
        uint2 uu; uu.x = u0; uu.y = u1;
        pa[qf][nf] = __builtin_bit_cast(s4, uu);
      }
    }

    __builtin_amdgcn_s_setprio(1);
    #pragma unroll
    for (int qf = 0; qf < 2; qf++)
      #pragma unroll
      for (int nf = 0; nf < 4; nf++)
        lac[qf] = MFMAH(pa[qf][nf], ones4, lac[qf]);
    #pragma unroll
    for (int nf = 0; nf < 4; nf++){
      #pragma unroll
      for (int nfd = 0; nfd < 4; nfd++){
        us4 bv = *reinterpret_cast<const us4*>(
            &Vs[cur][(nfd*16 + lr)*64 + (((nf*2 + (lg>>1)) ^ (lr & 7))*8) + (lg&1)*4]);
        O[0][nfd] = MFMAH(pa[0][nf], bv, O[0][nfd]);
        O[1][nfd] = MFMAH(pa[1][nf], bv, O[1][nfd]);
      }
    }
    __builtin_amdgcn_s_setprio(0);
    __builtin_amdgcn_s_barrier();
  }

  #pragma unroll
  for (int qf = 0; qf < 2; qf++)
    #pragma unroll
    for (int reg = 0; reg < 4; reg++){
      int qg = qt*128 + w*32 + qf*16 + lg*4 + reg;
      if (qg < NTOK){
        float inv = 1.0f / lac[qf][reg];
        #pragma unroll
        for (int nfd = 0; nfd < 4; nfd++)
          ao[(size_t)(b_ * NTOK + qg) * 1024 + h*64 + nfd*16 + lr] = f2bf(O[qf][nfd][reg] * inv);
      }
    }
}

// ---------------- proj GEMM: 256x128 tile, 8 waves, counted-vmcnt 2-phase ----------------
__global__ __launch_bounds__(512,4) void proj_gemm(
    const unsigned short* __restrict__ A,   // [MPAD][1024]
    const unsigned short* __restrict__ Bw,  // [1024][1024]
    const float* __restrict__ bias,
    float* __restrict__ out)
{
  const int K = 1024;
  __shared__ __align__(16) unsigned short As[2][256*32];
  __shared__ __align__(16) unsigned short Bs[2][128*32];
  int tid = threadIdx.x;
  int id = blockIdx.x;
  int work = (id & 7) * 33 + (id >> 3);        // 264 = 8 * 33
  int m0 = (work / 8) * 256, n0 = (work % 8) * 128;
  int w = tid >> 6, lane = tid & 63, lr = lane & 15, lg = lane >> 4;
  int wr = w >> 1, wc = w & 1;
  int srow = lane >> 2;
  int scol = ((lane & 3) ^ ((lane >> 3) & 3)) * 8;
  int sa = (lg ^ ((lr >> 1) & 3)) * 8;
  f32x4 acc[4][4] = {};

  auto stage = [&](int buf, int k0){
    gl_lds16(&A [(size_t)(m0 + w*32      + srow) * K + k0 + scol], &As[buf][(w*2  )*512]);
    gl_lds16(&A [(size_t)(m0 + w*32 + 16 + srow) * K + k0 + scol], &As[buf][(w*2+1)*512]);
    gl_lds16(&Bw[(size_t)(n0 + w*16      + srow) * K + k0 + scol], &Bs[buf][ w      *512]);
  };

  stage(0, 0);

  for (int kt = 0; kt < 32; kt++){
    int cur = kt & 1;
    if (kt < 31){
      stage(cur ^ 1, (kt + 1) * 32);
      asm volatile("s_waitcnt vmcnt(3)" ::: "memory");
    } else {
      asm volatile("s_waitcnt vmcnt(0)" ::: "memory");
    }
    __builtin_amdgcn_sched_barrier(0);
    __builtin_amdgcn_s_barrier();

    us8 a[4], b[4];
    #pragma unroll
    for (int mi = 0; mi < 4; mi++) a[mi] = *reinterpret_cast<const us8*>(&As[cur][(wr*64 + mi*16 + lr)*32 + sa]);
    #pragma unroll
    for (int ni = 0; ni < 4; ni++) b[ni] = *reinterpret_cast<const us8*>(&Bs[cur][(wc*64 + ni*16 + lr)*32 + sa]);
    #pragma unroll
    for (int mi = 0; mi < 4; mi++)
      #pragma unroll
      for (int ni = 0; ni < 4; ni++)
        acc[mi][ni] = MFMA16(a[mi], b[ni], acc[mi][ni]);
    __builtin_amdgcn_s_barrier();
  }

  #pragma unroll
  for (int mi = 0; mi < 4; mi++){
    #pragma unroll
    for (int ni = 0; ni < 4; ni++){
      #pragma unroll
      for (int reg = 0; reg < 4; reg++){
        int m = m0 + wr*64 + mi*16 + lg*4 + reg;
        if (m >= MTOT) continue;
        int n = n0 + wc*64 + ni*16 + lr;
        out[(size_t)m * 1024 + n] = acc[mi][ni][reg] + bias[n];
      }
    }
  }
}

extern "C" void kernel_launch(void* const* d_in, const int* in_sizes, int n_in,
                              void* d_out, int out_size, void* d_ws, size_t ws_size,
                              hipStream_t stream)
{
  const float* x      = (const float*)d_in[0];
  const float* qkv_w  = (const float*)d_in[1];
  const float* qkv_b  = (const float*)d_in[2];
  const float* proj_w = (const float*)d_in[3];
  const float* proj_b = (const float*)d_in[4];
  const float* rph    = (const float*)d_in[5];
  const float* rpw    = (const float*)d_in[6];
  float* out = (float*)d_out;

  char* ws = (char*)d_ws;
  size_t off = 0;
  auto alloc = [&](size_t bytes){ char* p = ws + off; off += (bytes + 255) & ~(size_t)255; return p; };
  unsigned short* x_bf  = (unsigned short*)alloc((size_t)MPAD * 1024 * 2);
  unsigned short* qw_bf = (unsigned short*)alloc((size_t)3072 * 1024 * 2);
  unsigned short* pw_bf = (unsigned short*)alloc((size_t)1024 * 1024 * 2);
  unsigned short* qbuf  = (unsigned short*)alloc((size_t)128 * NPAD * 64 * 2);
  unsigned short* kbuf  = (unsigned short*)alloc((size_t)128 * NPAD * 64 * 2);
  unsigned short* vtbuf = (unsigned short*)alloc((size_t)128 * 64 * NPAD * 2);
  unsigned short* aout  = (unsigned short*)alloc((size_t)MPAD * 1024 * 2);
  if (off > ws_size) return;

  // vb (normal-layout V, exactly MTOT*1024*2 B) aliases the live region of aout;
  // consumed by transpose_v before attn writes aout.
  unsigned short* vbuf = aout;

  const int n4x = MTOT * 1024 / 4, n4q = 3072 * 1024 / 4, n4p = 1024 * 1024 / 4;
  int ntot = n4x + n4q + n4p + 128 * (NPAD - NTOK) * 64 + 2 * (MPAD - MTOT) * 1024;
  prep<<<dim3((ntot + 255) / 256), 256, 0, stream>>>(x, qkv_w, proj_w,
                                                     x_bf, qw_bf, pw_bf,
                                                     qbuf, kbuf, aout);

  qkv_gemm<<<dim3(792), 512, 0, stream>>>(x_bf, qw_bf, qkv_b, qbuf, kbuf, vbuf);
  transpose_v<<<dim3(128 * 17), 256, 0, stream>>>(vbuf, vtbuf);
  attn_kernel<<<dim3(1152), 256, 0, stream>>>(qbuf, kbuf, vtbuf, rph, rpw, aout);
  proj_gemm<<<dim3(264), 512, 0, stream>>>(aout, pw_bf, proj_b, out);
}